// Round 14
// baseline (214.472 us; speedup 1.0000x reference)
//
#include <hip/hip_runtime.h>

#define NN 100000
#define NE 3200000
#define DD 64
#define KE 64                 // edges per worker (NE % KE == 0)
#define NW (NE / KE)          // 50000 sixteen-lane workers
#define GEMM_BLOCKS 391       // ceil(NN/256)
#define PREP_BLOCKS 12501     // ceil((NE+32)/256)

typedef unsigned int uint32;

// ---------------------------------------------------------------------------
// bf16 round-to-nearest-even of an f32 (inputs finite).
// ---------------------------------------------------------------------------
__device__ inline uint32 bf16_rne(float f) {
    uint32 u = __float_as_uint(f);
    return (u + 0x7fffu + ((u >> 16) & 1u)) >> 16;
}

// ---------------------------------------------------------------------------
// Dispatch 1: prep  ||  gemm1'  (independent work, block-range split).
// gemm1' blocks [0, GEMM_BLOCKS): xw[row,:] = bf16(x[row,:] @ W1)  (bias and
//   activation live in spmm1's flush).  One thread per row, W1 in LDS.
// prep blocks [GEMM_BLOCKS, ...): one thread per edge. Packed edge record
//   (bits 31..17 = bf16(val) sans sign, val>=0; bits 16..0 = col), rp[] span
//   fill from the sorted row stream, fused worker-start table ws[], 32 zero
//   pad records for masked batch overrun. Inline int64/int32 detection.
// ---------------------------------------------------------------------------
__global__ __launch_bounds__(256) void pre_kernel(
    const void* rowbuf, const void* colbuf, const float* __restrict__ val,
    const float* __restrict__ x, const float* __restrict__ W1,
    uint32* __restrict__ erec, int* __restrict__ rp, int* __restrict__ ws,
    uint32* __restrict__ xw) {
    __shared__ float4 sW[DD * 16];   // sW[k*16+j4] = W1[k][4j4..4j4+3]

    if (blockIdx.x < GEMM_BLOCKS) {
        for (int i = threadIdx.x; i < DD * 16; i += 256)
            sW[i] = ((const float4*)W1)[i];
        __syncthreads();

        int row = blockIdx.x * 256 + threadIdx.x;
        if (row >= NN) return;

        float acc[DD];
#pragma unroll
        for (int j = 0; j < DD; ++j) acc[j] = 0.f;

        const float4* Bp = (const float4*)(x + (size_t)row * DD);
#pragma unroll
        for (int k4 = 0; k4 < 16; ++k4) {
            float4 x4 = Bp[k4];
            float xs[4] = {x4.x, x4.y, x4.z, x4.w};
#pragma unroll
            for (int kk = 0; kk < 4; ++kk) {
                float xk = xs[kk];
                int k = 4 * k4 + kk;
#pragma unroll
                for (int j4 = 0; j4 < 16; ++j4) {
                    float4 w = sW[k * 16 + j4];
                    acc[4 * j4 + 0] = fmaf(xk, w.x, acc[4 * j4 + 0]);
                    acc[4 * j4 + 1] = fmaf(xk, w.y, acc[4 * j4 + 1]);
                    acc[4 * j4 + 2] = fmaf(xk, w.z, acc[4 * j4 + 2]);
                    acc[4 * j4 + 3] = fmaf(xk, w.w, acc[4 * j4 + 3]);
                }
            }
        }
        uint32* o = xw + (size_t)row * 32;
#pragma unroll
        for (int q = 0; q < 32; ++q)
            o[q] = bf16_rne(acc[2 * q]) | (bf16_rne(acc[2 * q + 1]) << 16);
        return;
    }

    // ---- prep branch ----
    int e = (blockIdx.x - GEMM_BLOCKS) * 256 + threadIdx.x;
    if (e >= NE + 32) return;
    if (e >= NE) { erec[e] = 0u; return; }

    const int* p32 = (const int*)rowbuf;
    bool is64 = (p32[NE / 2 + 1] == 0 && p32[NE / 2] != 0);

    int r, rn, c;
    if (is64) {
        const long long* row = (const long long*)rowbuf;
        const long long* col = (const long long*)colbuf;
        r  = (int)row[e];
        rn = (e == NE - 1) ? NN : (int)row[e + 1];
        c  = (int)col[e];
    } else {
        const int* row = (const int*)rowbuf;
        const int* col = (const int*)colbuf;
        r  = row[e];
        rn = (e == NE - 1) ? NN : row[e + 1];
        c  = col[e];
    }
    erec[e] = ((bf16_rne(val[e]) & 0x7fffu) << 17) | (uint32)c;
    for (int q = r + 1; q <= rn; ++q) rp[q] = e + 1;
    if (e == 0) {
        for (int q = 0; q <= r; ++q) rp[q] = 0;
        ws[0]  = 0;
        ws[NW] = NN;
    }
    if (((e + 1) & (KE - 1)) == 0 && (e + 1) < NE)
        ws[(e + 1) / KE] = r + 1;
}

// ---------------------------------------------------------------------------
// SpMM: r11's fastest structure, unmodified memory behavior (no nontemporal
// hints). 16-lane workers with exclusive row ownership; lane sl holds
// features {4sl..4sl+3} (one uint2 = 128 B/row gather, 1 load per edge).
// 16-deep gather pipeline (4 workers/wave -> 64 edges in flight per wave).
// Flush adds bias (+LeakyReLU+bf16-pack for layer 1; f32 float4 store for
// layer 2), stores each row exactly once. Overrun edges masked to record 0.
// ---------------------------------------------------------------------------
#define ISSUE(G, U, I) {                                        \
    U = (uint32)__shfl((int)rw, (I), 16);                       \
    G = ((const uint2*)Xq)[((U & 0x1ffffu) << 4) + sl]; }

#define FLUSH() {                                                       \
    float y0 = a0 + bv.x, y1 = a1 + bv.y,                               \
          y2 = a2 + bv.z, y3 = a3 + bv.w;                               \
    if (L1) {                                                           \
        y0 = (y0 >= 0.f) ? y0 : 0.2f * y0;                              \
        y1 = (y1 >= 0.f) ? y1 : 0.2f * y1;                              \
        y2 = (y2 >= 0.f) ? y2 : 0.2f * y2;                              \
        y3 = (y3 >= 0.f) ? y3 : 0.2f * y3;                              \
        uint2 pk_;                                                      \
        pk_.x = bf16_rne(y0) | (bf16_rne(y1) << 16);                    \
        pk_.y = bf16_rne(y2) | (bf16_rne(y3) << 16);                    \
        ((uint2*)obv)[(size_t)rr * 16 + sl] = pk_;                      \
    } else {                                                            \
        float4 f4_ = make_float4(y0, y1, y2, y3);                       \
        ((float4*)obv)[(size_t)rr * 16 + sl] = f4_;                     \
    }                                                                   \
    a0 = 0.f; a1 = 0.f; a2 = 0.f; a3 = 0.f; ++rr; }

#define ACCUM(G, U, I) {                                        \
    while (e0 + (I) >= re) {                                    \
        FLUSH();                                                \
        re = (rr < r1) ? rp[rr + 1] : 0x7fffffff;               \
    }                                                           \
    float vi_ = __uint_as_float((U >> 17) << 16);               \
    a0 = fmaf(vi_, __uint_as_float(G.x << 16),          a0);    \
    a1 = fmaf(vi_, __uint_as_float(G.x & 0xffff0000u),  a1);    \
    a2 = fmaf(vi_, __uint_as_float(G.y << 16),          a2);    \
    a3 = fmaf(vi_, __uint_as_float(G.y & 0xffff0000u),  a3); }

template <bool L1>
__global__ __launch_bounds__(256) void spmm_kernel(
    const uint32* __restrict__ Xq, const uint32* __restrict__ erec,
    const int* __restrict__ rp, const int* __restrict__ ws,
    const float* __restrict__ bias, void* __restrict__ obv) {
    int worker = (blockIdx.x * blockDim.x + threadIdx.x) >> 4;
    int sl = threadIdx.x & 15;
    if (worker >= NW) return;

    int rr = ws[worker];
    int r1 = ws[worker + 1];
    if (rr >= r1) return;

    const float4 bv = ((const float4*)bias)[sl];   // bias[4sl .. 4sl+3]

    int eb = rp[rr];
    int ee = rp[r1];
    int re = rp[rr + 1];
    float a0 = 0.f, a1 = 0.f, a2 = 0.f, a3 = 0.f;

    for (int e0 = eb; e0 < ee; e0 += 16) {
        uint32 rw = erec[e0 + sl];           // padded: always in-bounds
        rw = (e0 + sl < ee) ? rw : 0u;       // mask overrun -> row 0, val 0
        uint2  g0, g1, g2, g3, g4, g5, g6, g7;
        uint2  h0, h1, h2, h3, h4, h5, h6, h7;
        uint32 u0, u1, u2, u3, u4, u5, u6, u7;
        uint32 w0, w1, w2, w3, w4, w5, w6, w7;
        ISSUE(g0, u0, 0)  ISSUE(g1, u1, 1)  ISSUE(g2, u2, 2)  ISSUE(g3, u3, 3)
        ISSUE(g4, u4, 4)  ISSUE(g5, u5, 5)  ISSUE(g6, u6, 6)  ISSUE(g7, u7, 7)
        ISSUE(h0, w0, 8)  ISSUE(h1, w1, 9)  ISSUE(h2, w2, 10) ISSUE(h3, w3, 11)
        ISSUE(h4, w4, 12) ISSUE(h5, w5, 13) ISSUE(h6, w6, 14) ISSUE(h7, w7, 15)
        ACCUM(g0, u0, 0)  ACCUM(g1, u1, 1)  ACCUM(g2, u2, 2)  ACCUM(g3, u3, 3)
        ACCUM(g4, u4, 4)  ACCUM(g5, u5, 5)  ACCUM(g6, u6, 6)  ACCUM(g7, u7, 7)
        ACCUM(h0, w0, 8)  ACCUM(h1, w1, 9)  ACCUM(h2, w2, 10) ACCUM(h3, w3, 11)
        ACCUM(h4, w4, 12) ACCUM(h5, w5, 13) ACCUM(h6, w6, 14) ACCUM(h7, w7, 15)
    }
    // drain: last row + trailing empty rows (bias-only rows handled too)
    while (rr < r1) { FLUSH(); }
}

// ---------------------------------------------------------------------------
// Dispatch 3: gemm2'  g[row,:] = bf16(unpack(h[row,:]) @ W2)  (bias2 lives
// in spmm2's flush).
// ---------------------------------------------------------------------------
__global__ __launch_bounds__(256) void gemm_bb_kernel(
    const uint32* __restrict__ Bb, const float* __restrict__ W,
    uint32* __restrict__ ob) {
    __shared__ float4 sW[DD * 16];
    for (int i = threadIdx.x; i < DD * 16; i += 256)
        sW[i] = ((const float4*)W)[i];
    __syncthreads();

    int row = blockIdx.x * 256 + threadIdx.x;
    if (row >= NN) return;

    float acc[DD];
#pragma unroll
    for (int j = 0; j < DD; ++j) acc[j] = 0.f;

    const uint4* Bp = (const uint4*)(Bb + (size_t)row * 32);
#pragma unroll
    for (int q4 = 0; q4 < 8; ++q4) {
        uint4 u4 = Bp[q4];
        uint32 us[4] = {u4.x, u4.y, u4.z, u4.w};
#pragma unroll
        for (int t = 0; t < 4; ++t) {
            int k = q4 * 8 + t * 2;
            float x0 = __uint_as_float(us[t] << 16);
            float x1 = __uint_as_float(us[t] & 0xffff0000u);
#pragma unroll
            for (int j4 = 0; j4 < 16; ++j4) {
                float4 w0 = sW[k * 16 + j4];
                float4 w1 = sW[(k + 1) * 16 + j4];
                acc[4 * j4 + 0] = fmaf(x0, w0.x, acc[4 * j4 + 0]);
                acc[4 * j4 + 1] = fmaf(x0, w0.y, acc[4 * j4 + 1]);
                acc[4 * j4 + 2] = fmaf(x0, w0.z, acc[4 * j4 + 2]);
                acc[4 * j4 + 3] = fmaf(x0, w0.w, acc[4 * j4 + 3]);
                acc[4 * j4 + 0] = fmaf(x1, w1.x, acc[4 * j4 + 0]);
                acc[4 * j4 + 1] = fmaf(x1, w1.y, acc[4 * j4 + 1]);
                acc[4 * j4 + 2] = fmaf(x1, w1.z, acc[4 * j4 + 2]);
                acc[4 * j4 + 3] = fmaf(x1, w1.w, acc[4 * j4 + 3]);
            }
        }
    }

    uint32* o = ob + (size_t)row * 32;
#pragma unroll
    for (int q = 0; q < 32; ++q)
        o[q] = bf16_rne(acc[2 * q]) | (bf16_rne(acc[2 * q + 1]) << 16);
}

// ---------------------------------------------------------------------------
extern "C" void kernel_launch(void* const* d_in, const int* in_sizes, int n_in,
                              void* d_out, int out_size, void* d_ws, size_t ws_size,
                              hipStream_t stream) {
    const float* x       = (const float*)d_in[0];
    const void*  adj_row = d_in[1];
    const void*  adj_col = d_in[2];
    const float* adj_val = (const float*)d_in[3];
    const float* W1      = (const float*)d_in[4];
    const float* b1      = (const float*)d_in[5];
    const float* W2      = (const float*)d_in[6];
    const float* b2      = (const float*)d_in[7];
    float*       out     = (float*)d_out;

    // ws: bufA(h) [NN*32 u32] | bufB(xW1/hW2) [NN*32 u32] | erec | rp | ws
    uint32* bufA = (uint32*)d_ws;
    uint32* bufB = bufA + (size_t)NN * 32;
    uint32* erec = bufB + (size_t)NN * 32;
    int*    rp   = (int*)(erec + NE + 32);
    int*    wst  = rp + (NN + 1);

    const int spmm_blocks = (NW * 16) / 256;   // 3125

    // 1. prep || gemm1' : erec/rp/ws + bufB = bf16(x W1)
    pre_kernel<<<GEMM_BLOCKS + PREP_BLOCKS, 256, 0, stream>>>(
        adj_row, adj_col, adj_val, x, W1, erec, rp, wst, bufB);

    // 2. spmm1: bufA = bf16(LReLU(A bufB + b1))
    spmm_kernel<true><<<spmm_blocks, 256, 0, stream>>>(bufB, erec, rp, wst,
                                                       b1, bufA);

    // 3. gemm2': bufB = bf16(bufA W2)
    gemm_bb_kernel<<<GEMM_BLOCKS, 256, 0, stream>>>(bufA, W2, bufB);

    // 4. spmm2: out = A bufB + b2   (f32, float4 stores)
    spmm_kernel<false><<<spmm_blocks, 256, 0, stream>>>(bufB, erec, rp, wst,
                                                        b2, out);
}